// Round 2
// baseline (494595.654 us; speedup 1.0000x reference)
//
#include <hip/hip_runtime.h>
#include <cstdint>

// B=64 T=512 S=500 M=80 E=512 P=256 H=1024 A=128 F_LOC=32 K_LOC=31
// Persistent-kernel design: 1 kernel, 500 steps, 4 grid barriers/step.
// Stage A: attn-GEMM(s) + dec-GEMM(s-1)   [global-direct fp32 GEMM, no LDS]
// Stage B: attn pointwise+dropout+q(s) + dec pointwise+mel/gate(s-1)
// Stage C: location conv + energies + exp + tile sums (s)
// Stage D: softmax normalize + alignments + ctx (s)

#define NB 512

// ---------------- workspace float offsets ----------------
#define OFF_PM      0u          // 64*512*128
#define OFF_PRENETT 4194304u    // [500][256][64]
#define OFF_PARTA   12386304u   // 7 *64*4096
#define OFF_PARTD   14221312u   // 10*64*4096
#define OFF_QPART   16842752u   // 4*64*128
#define OFF_PEXP    16875520u   // 64*512
#define OFF_ESUM    16908288u   // 64*8
#define OFF_AHT     16908800u   // [1024][64]
#define OFF_AC      16974336u   // [64][1024]
#define OFF_DHT     17039872u   // [1024][64]
#define OFF_DC      17105408u   // [64][1024]
#define OFF_AW      17170944u   // [64][512]
#define OFF_AWC     17203712u
#define OFF_CTXT    17236480u   // [512][64]
#define OFF_WQT     17269248u   // [1024][128]
#define OFF_PWT     17400320u   // [1536][81]
#define OFF_KF      17524736u   // 2000 u32
#define OFF_BAR     17526784u   // barrier counter
#define WS_FLOATS_NEEDED 17526848u

// ---------------- threefry RNG (JAX partitionable, scheme 0) ----------------
__device__ __forceinline__ void tf2x32(uint32_t k0, uint32_t k1, uint32_t& x0, uint32_t& x1) {
  uint32_t ks2 = k0 ^ k1 ^ 0x1BD11BDAu;
  x0 += k0; x1 += k1;
#define TFR(r) { x0 += x1; x1 = (x1 << (r)) | (x1 >> (32 - (r))); x1 ^= x0; }
  TFR(13) TFR(15) TFR(26) TFR(6)
  x0 += k1; x1 += ks2 + 1u;
  TFR(17) TFR(29) TFR(16) TFR(24)
  x0 += ks2; x1 += k0 + 2u;
  TFR(13) TFR(15) TFR(26) TFR(6)
  x0 += k0; x1 += k1 + 3u;
  TFR(17) TFR(29) TFR(16) TFR(24)
  x0 += k1; x1 += ks2 + 4u;
  TFR(13) TFR(15) TFR(26) TFR(6)
  x0 += ks2; x1 += k0 + 5u;
#undef TFR
}

__device__ __forceinline__ float rng_u01(uint32_t k0, uint32_t k1, uint32_t idx) {
  uint32_t x0 = 0u, x1 = idx;
  tf2x32(k0, k1, x0, x1);
  uint32_t b = x0 ^ x1;
  return __uint_as_float((b >> 9) | 0x3f800000u) - 1.0f;
}

__device__ __forceinline__ float sigmf(float x) { return 1.0f / (1.0f + expf(-x)); }

// ---------------- grid barrier (monotonic counter) ----------------
__device__ __forceinline__ void grid_sync(int* bar, int target) {
  __syncthreads();
  if (threadIdx.x == 0) {
    __threadfence();
    __hip_atomic_fetch_add(bar, 1, __ATOMIC_ACQ_REL, __HIP_MEMORY_SCOPE_AGENT);
    while (__hip_atomic_load(bar, __ATOMIC_ACQUIRE, __HIP_MEMORY_SCOPE_AGENT) < target)
      __builtin_amdgcn_s_sleep(2);
  }
  __syncthreads();
}

// ---------------- prep kernels ----------------
__global__ void k_fold(uint32_t* __restrict__ kf) {
  int t = blockIdx.x * 256 + threadIdx.x;
  if (t < 1000) {
    uint32_t x0 = 0u, x1 = (uint32_t)t;
    tf2x32(0u, 7u, x0, x1);
    kf[2 * t] = x0; kf[2 * t + 1] = x1;
  }
}

__global__ __launch_bounds__(256) void k_pm(const float* __restrict__ mem,
                                            const float* __restrict__ wm,
                                            float* __restrict__ pm) {
  const int row0 = blockIdx.x * 8;  // flat (b*512+t)
  __shared__ float sm[8][512];
  const float4* src = (const float4*)(mem + (size_t)row0 * 512);
  float4* dst = (float4*)&sm[0][0];
  for (int i = threadIdx.x; i < 8 * 128; i += 256) dst[i] = src[i];
  __syncthreads();
  const int a = threadIdx.x & 127;
  const int rh = threadIdx.x >> 7;
  float acc[4] = {0.f, 0.f, 0.f, 0.f};
  for (int e = 0; e < 512; e += 4) {
    float4 w4 = *(const float4*)&wm[a * 512 + e];
#pragma unroll
    for (int r = 0; r < 4; r++) {
      acc[r] += sm[rh * 4 + r][e] * w4.x + sm[rh * 4 + r][e + 1] * w4.y +
                sm[rh * 4 + r][e + 2] * w4.z + sm[rh * 4 + r][e + 3] * w4.w;
    }
  }
#pragma unroll
  for (int r = 0; r < 4; r++) pm[(size_t)(row0 + rh * 4 + r) * 128 + a] = acc[r];
}

__global__ __launch_bounds__(256) void k_prenet1(const float* __restrict__ din,
                                                 const float* __restrict__ w1,
                                                 float* __restrict__ tmp1) {
  const int r0 = blockIdx.x * 8;
  const int tid = threadIdx.x;
  __shared__ float xin[8][80];
  for (int i = tid; i < 640; i += 256) {
    int rr = i / 80, k = i - rr * 80;
    int r = r0 + rr;
    int s = r >> 6, b = r & 63;
    xin[rr][k] = (s == 0) ? 0.0f : din[((size_t)b * 500 + (s - 1)) * 80 + k];
  }
  __syncthreads();
  const int j = tid;
  float acc[8] = {};
  for (int k = 0; k < 80; k++) {
    float wv = w1[j * 80 + k];
#pragma unroll
    for (int i = 0; i < 8; i++) acc[i] += xin[i][k] * wv;
  }
#pragma unroll
  for (int i = 0; i < 8; i++) {
    int r = r0 + i;
    float x = fmaxf(acc[i], 0.0f);
    float u = rng_u01(0u, 101u, (uint32_t)(r * 256 + j));
    x = (u < 0.5f) ? x * 2.0f : 0.0f;
    tmp1[(size_t)r * 256 + j] = x;
  }
}

__global__ __launch_bounds__(256) void k_prenet2(const float* __restrict__ tmp1,
                                                 const float* __restrict__ w2,
                                                 float* __restrict__ prenetT) {
  const int r0 = blockIdx.x * 8;
  const int s = r0 >> 6, b0 = r0 & 63;
  const int tid = threadIdx.x;
  __shared__ float xin[8][256];
  for (int i = tid; i < 2048; i += 256) xin[i >> 8][i & 255] = tmp1[(size_t)r0 * 256 + i];
  __syncthreads();
  const int j = tid;
  float acc[8] = {};
  for (int k = 0; k < 256; k++) {
    float wv = w2[j * 256 + k];
#pragma unroll
    for (int i = 0; i < 8; i++) acc[i] += xin[i][k] * wv;
  }
  float v[8];
#pragma unroll
  for (int i = 0; i < 8; i++) {
    int r = r0 + i;
    float x = fmaxf(acc[i], 0.0f);
    float u = rng_u01(0u, 102u, (uint32_t)(r * 256 + j));
    v[i] = (u < 0.5f) ? x * 2.0f : 0.0f;
  }
  float* dstp = prenetT + (size_t)s * 16384 + (size_t)j * 64 + b0;
  *(float4*)dstp = make_float4(v[0], v[1], v[2], v[3]);
  *(float4*)(dstp + 4) = make_float4(v[4], v[5], v[6], v[7]);
}

__global__ void k_prep_wq(const float* __restrict__ wq, float* __restrict__ wqT) {
  int idx = blockIdx.x * 256 + threadIdx.x;  // 1024*128
  if (idx < 131072) { int h = idx >> 7, a = idx & 127; wqT[idx] = wq[a * 1024 + h]; }
}

__global__ void k_prep_pw(const float* __restrict__ projw, const float* __restrict__ gatew,
                          float* __restrict__ pwT) {
  int idx = blockIdx.x * 256 + threadIdx.x;  // 1536*81
  if (idx < 124416) {
    int dim = idx / 81, m = idx - dim * 81;
    pwT[idx] = (m < 80) ? projw[(size_t)m * 1536 + dim] : gatew[dim];
  }
}

// ---------------- global-direct GEMM tile: 64j x 64b x 256k ----------------
// xT: [k][64b] transposed activations. w: row-major [j][K]. Writes part slab [b][4096].
__device__ __forceinline__ void gemm_tile(const float* __restrict__ xT,
                                          const float* __restrict__ w, int wst, int wcol,
                                          int j0, float* __restrict__ slab) {
  const int tid = threadIdx.x;
  const int bq4 = (tid & 15) * 4;
  const int jr0 = j0 + (tid >> 4) * 4;
  const float* wr0 = w + (size_t)jr0 * wst + wcol;
  const float* wr1 = wr0 + wst;
  const float* wr2 = wr1 + wst;
  const float* wr3 = wr2 + wst;
  float acc[4][4] = {};
#define FMAROW(jr, wv, xv) { acc[jr][0] += (wv)*(xv).x; acc[jr][1] += (wv)*(xv).y; \
                             acc[jr][2] += (wv)*(xv).z; acc[jr][3] += (wv)*(xv).w; }
  for (int k = 0; k < 256; k += 4) {
    float4 x0 = *(const float4*)(xT + (k + 0) * 64 + bq4);
    float4 x1 = *(const float4*)(xT + (k + 1) * 64 + bq4);
    float4 x2 = *(const float4*)(xT + (k + 2) * 64 + bq4);
    float4 x3 = *(const float4*)(xT + (k + 3) * 64 + bq4);
    float4 w0 = *(const float4*)(wr0 + k);
    float4 w1 = *(const float4*)(wr1 + k);
    float4 w2 = *(const float4*)(wr2 + k);
    float4 w3 = *(const float4*)(wr3 + k);
    FMAROW(0, w0.x, x0) FMAROW(1, w1.x, x0) FMAROW(2, w2.x, x0) FMAROW(3, w3.x, x0)
    FMAROW(0, w0.y, x1) FMAROW(1, w1.y, x1) FMAROW(2, w2.y, x1) FMAROW(3, w3.y, x1)
    FMAROW(0, w0.z, x2) FMAROW(1, w1.z, x2) FMAROW(2, w2.z, x2) FMAROW(3, w3.z, x2)
    FMAROW(0, w0.w, x3) FMAROW(1, w1.w, x3) FMAROW(2, w2.w, x3) FMAROW(3, w3.w, x3)
  }
#undef FMAROW
#pragma unroll
  for (int bb = 0; bb < 4; bb++) {
    *(float4*)&slab[(size_t)((tid & 15) * 4 + bb) * 4096 + jr0] =
        make_float4(acc[0][bb], acc[1][bb], acc[2][bb], acc[3][bb]);
  }
}

// ---------------- shared-memory union ----------------
struct EnS { float sa[2][96]; float sq[128]; float sv[128]; float sw[1984];
             float sld[4096]; float sloc[64][33]; float spart[64][4]; };
struct SbS { float ahs[256]; float qred[256]; };
struct SdS { float dhn[256]; float red[256]; };
struct SxS { float se[512]; float red[256]; };
union ShU { EnS en; SbS sb; SdS sd; SxS sx; };

// ---------------- the persistent kernel ----------------
__global__ __launch_bounds__(256, 2) void k_persist(
    const float* __restrict__ memory, const int* __restrict__ mlen,
    const float* __restrict__ awih, const float* __restrict__ awhh,
    const float* __restrict__ abih, const float* __restrict__ abhh,
    const float* __restrict__ dwih, const float* __restrict__ dwhh,
    const float* __restrict__ dbih, const float* __restrict__ dbhh,
    const float* __restrict__ wconv, const float* __restrict__ wld,
    const float* __restrict__ av,
    const float* __restrict__ projb, const float* __restrict__ gateb,
    float* __restrict__ out_mel, float* __restrict__ out_gate,
    float* __restrict__ out_align, float* __restrict__ ws) {
  const int bid = blockIdx.x, tid = threadIdx.x;
  float* pm      = ws + OFF_PM;
  float* prenetT = ws + OFF_PRENETT;
  float* part_a  = ws + OFF_PARTA;
  float* part_d  = ws + OFF_PARTD;
  float* qpart   = ws + OFF_QPART;
  float* pexp    = ws + OFF_PEXP;
  float* esum    = ws + OFF_ESUM;
  float* ahT     = ws + OFF_AHT;
  float* ac      = ws + OFF_AC;
  float* dhT     = ws + OFF_DHT;
  float* dc      = ws + OFF_DC;
  float* aw      = ws + OFF_AW;
  float* awc     = ws + OFF_AWC;
  float* ctxT    = ws + OFF_CTXT;
  float* wqT     = ws + OFF_WQT;
  float* pwT     = ws + OFF_PWT;
  const uint32_t* kf = (const uint32_t*)(ws + OFF_KF);
  int* bar = (int*)(ws + OFF_BAR);

  __shared__ ShU sh;

  int phase = 0;
  for (int i = 0; i <= 500; ++i) {
    // ================= Stage A: GEMMs (+ zero mel/gate slice s=i-1) =================
    if (i >= 1 && bid < 64) {
      if (tid < 80) out_mel[(size_t)bid * 40000 + (size_t)(i - 1) * 80 + tid] = 0.f;
      else if (tid == 80) out_gate[bid * 500 + (i - 1)] = 0.f;
    }
    for (int task = bid; task < 1088; task += NB) {
      if (task < 448) {
        if (i < 500) {
          int jt = task / 7, kc = task - jt * 7;
          const float* xT; const float* w; int wst, wcol;
          if (kc == 0)      { xT = prenetT + (size_t)i * 16384; w = awih; wst = 768; wcol = 0; }
          else if (kc <= 2) { xT = ctxT + (size_t)(kc - 1) * 16384; w = awih; wst = 768; wcol = kc * 256; }
          else              { xT = ahT + (size_t)(kc - 3) * 16384; w = awhh; wst = 1024; wcol = (kc - 3) * 256; }
          gemm_tile(xT, w, wst, wcol, jt * 64, part_a + (size_t)kc * 262144);
        }
      } else {
        if (i >= 1) {
          int t2 = task - 448;
          int jt = t2 / 10, kc = t2 - jt * 10;
          const float* xT; const float* w; int wst, wcol;
          if (kc <= 3)      { xT = ahT + (size_t)kc * 16384; w = dwih; wst = 1536; wcol = kc * 256; }
          else if (kc <= 5) { xT = ctxT + (size_t)(kc - 4) * 16384; w = dwih; wst = 1536; wcol = 1024 + (kc - 4) * 256; }
          else              { xT = dhT + (size_t)(kc - 6) * 16384; w = dwhh; wst = 1024; wcol = (kc - 6) * 256; }
          gemm_tile(xT, w, wst, wcol, jt * 64, part_d + (size_t)kc * 262144);
        }
      }
    }
    phase++; grid_sync(bar, phase * NB);

    // ================= Stage B: pointwise =================
    if (bid < 256) {
      if (i < 500) {  // attn LSTM pointwise + dropout + q partial
        const int b = bid >> 2, hblk = bid & 3;
        const int h = hblk * 256 + tid;
        const float* pa = part_a + (size_t)b * 4096 + h;
        float gi = abih[h] + abhh[h];
        float gf = abih[1024 + h] + abhh[1024 + h];
        float gg = abih[2048 + h] + abhh[2048 + h];
        float go = abih[3072 + h] + abhh[3072 + h];
#pragma unroll
        for (int p = 0; p < 7; p++) {
          const float* pp = pa + (size_t)p * 262144;
          gi += pp[0]; gf += pp[1024]; gg += pp[2048]; go += pp[3072];
        }
        float c = sigmf(gf) * ac[b * 1024 + h] + sigmf(gi) * tanhf(gg);
        float hn = sigmf(go) * tanhf(c);
        ac[b * 1024 + h] = c;
        float u = rng_u01(kf[4 * i], kf[4 * i + 1], (uint32_t)(b * 1024 + h));
        hn = (u < 0.9f) ? hn / 0.9f : 0.0f;
        ahT[(size_t)h * 64 + b] = hn;
        sh.sb.ahs[tid] = hn;
        __syncthreads();
        const int a = tid & 127, hh = tid >> 7;
        const float* wqp = wqT + (size_t)(hblk * 256 + hh * 128) * 128 + a;
        const float* hp = sh.sb.ahs + hh * 128;
        float acq = 0;
#pragma unroll 4
        for (int k = 0; k < 128; k++) acq += hp[k] * wqp[(size_t)k * 128];
        sh.sb.qred[tid] = acq;
        __syncthreads();
        if (tid < 128) qpart[hblk * 8192 + b * 128 + tid] = sh.sb.qred[tid] + sh.sb.qred[128 + tid];
      }
    } else {
      if (i >= 1) {  // dec LSTM pointwise + dropout + mel/gate partial
        const int u2 = bid - 256, b = u2 >> 2, hblk = u2 & 3, so = i - 1;
        const int h = hblk * 256 + tid;
        const float* pd = part_d + (size_t)b * 4096 + h;
        float gi = dbih[h] + dbhh[h];
        float gf = dbih[1024 + h] + dbhh[1024 + h];
        float gg = dbih[2048 + h] + dbhh[2048 + h];
        float go = dbih[3072 + h] + dbhh[3072 + h];
#pragma unroll
        for (int p = 0; p < 10; p++) {
          const float* pp = pd + (size_t)p * 262144;
          gi += pp[0]; gf += pp[1024]; gg += pp[2048]; go += pp[3072];
        }
        float c = sigmf(gf) * dc[b * 1024 + h] + sigmf(gi) * tanhf(gg);
        float hn = sigmf(go) * tanhf(c);
        dc[b * 1024 + h] = c;
        float u = rng_u01(kf[4 * so + 2], kf[4 * so + 3], (uint32_t)(b * 1024 + h));
        hn = (u < 0.9f) ? hn / 0.9f : 0.0f;
        dhT[(size_t)h * 64 + b] = hn;
        sh.sd.dhn[tid] = hn;
        __syncthreads();
        float partial = 0.f;
        if (tid < 162) {
          const int seg = (tid >= 81) ? 1 : 0;
          const int m = tid - seg * 81;
          const int dbase = hblk * 256 + seg * 128;
          const float* pwp = pwT + (size_t)dbase * 81 + m;
          float a1 = 0;
#pragma unroll 4
          for (int d = 0; d < 128; d++) a1 += sh.sd.dhn[seg * 128 + d] * pwp[(size_t)d * 81];
          if (hblk < 2) {
            const int ebase = hblk * 256 + seg * 128;
            const float* pwc = pwT + (size_t)(1024 + ebase) * 81 + m;
            const float* cxp = ctxT + (size_t)ebase * 64 + b;
#pragma unroll 4
            for (int d = 0; d < 128; d++) a1 += cxp[(size_t)d * 64] * pwc[(size_t)d * 81];
          }
          partial = a1;
        }
        sh.sd.red[tid] = partial;
        __syncthreads();
        if (tid < 81) {
          float tot = sh.sd.red[tid] + sh.sd.red[81 + tid];
          if (hblk == 0) tot += (tid < 80) ? projb[tid] : gateb[0];
          if (tid < 80) atomicAdd(&out_mel[(size_t)b * 40000 + (size_t)so * 80 + tid], tot);
          else          atomicAdd(&out_gate[b * 500 + so], tot);
        }
      }
    }
    phase++; grid_sync(bar, phase * NB);

    if (i < 500) {
      // ================= Stage C: energies → exp + tile sums =================
      {
        const int b = bid >> 3, ttile = bid & 7, t0 = ttile * 64;
        const int t = tid & 63, aq = tid >> 6;
        for (int i2 = tid; i2 < 94; i2 += 256) {
          int tt = t0 - 15 + i2;
          bool ok = (tt >= 0 && tt < 512);
          sh.en.sa[0][i2] = ok ? aw[b * 512 + tt] : 0.0f;
          sh.en.sa[1][i2] = ok ? awc[b * 512 + tt] : 0.0f;
        }
        if (tid < 128) {
          sh.en.sq[tid] = qpart[b * 128 + tid] + qpart[8192 + b * 128 + tid] +
                          qpart[16384 + b * 128 + tid] + qpart[24576 + b * 128 + tid];
          sh.en.sv[tid] = av[tid];
        }
        for (int i2 = tid; i2 < 1984; i2 += 256) sh.en.sw[i2] = wconv[i2];
        for (int i2 = tid; i2 < 4096; i2 += 256) sh.en.sld[i2] = wld[i2];
        __syncthreads();
        const int len = mlen[b];
        const int tt = t0 + t;
        const bool act2 = (tt < len);
        if (act2) {
          for (int f = aq * 8; f < aq * 8 + 8; f++) {
            const float* w0 = sh.en.sw + f * 62;
            const float* w1 = w0 + 31;
            float a2 = 0;
#pragma unroll
            for (int k = 0; k < 31; k++) a2 += sh.en.sa[0][t + k] * w0[k] + sh.en.sa[1][t + k] * w1[k];
            sh.en.sloc[t][f] = a2;
          }
        }
        __syncthreads();
        if (act2) {
          const float* pmr = pm + (size_t)(b * 512 + tt) * 128;
          float acc2 = 0;
          for (int a = aq * 32; a < aq * 32 + 32; a++) {
            float pl = 0;
#pragma unroll
            for (int f = 0; f < 32; f++) pl += sh.en.sloc[t][f] * sh.en.sld[a * 32 + f];
            float x = sh.en.sq[a] + pl + pmr[a];
            float ex = __expf(2.0f * x);
            acc2 += sh.en.sv[a] * (1.0f - 2.0f / (ex + 1.0f));
          }
          sh.en.spart[t][aq] = acc2;
        }
        __syncthreads();
        if (tid < 64) {
          int g = t0 + tid;
          float pe = 0.0f;
          if (g < len) {
            float e = (sh.en.spart[tid][0] + sh.en.spart[tid][1]) +
                      (sh.en.spart[tid][2] + sh.en.spart[tid][3]);
            pe = __expf(e);  // |e| <= sum|v| ~ 2, no max-subtraction needed
          }
          pexp[b * 512 + g] = pe;
          float ssum = pe;
          for (int off = 32; off > 0; off >>= 1) ssum += __shfl_down(ssum, off);
          if (tid == 0) esum[b * 8 + ttile] = ssum;
        }
      }
      phase++; grid_sync(bar, phase * NB);

      // ================= Stage D: normalize + alignments + ctx =================
      {
        const int b = bid >> 3, eblk = bid & 7;
        const int len = mlen[b];
        float S = 0;
#pragma unroll
        for (int p = 0; p < 8; p++) S += esum[b * 8 + p];
        const float rS = 1.0f / S;
        for (int t2 = tid; t2 < 512; t2 += 256) sh.sx.se[t2] = pexp[b * 512 + t2] * rS;
        __syncthreads();
        if (eblk == 0) {
          for (int t2 = tid; t2 < 512; t2 += 256) {
            float a2 = sh.sx.se[t2];
            aw[b * 512 + t2] = a2;
            awc[b * 512 + t2] += a2;
            out_align[(size_t)b * 256000 + (size_t)i * 512 + t2] = a2;
          }
        }
        const int e = eblk * 64 + (tid & 63), tq = tid >> 6;
        const float* mb = memory + (size_t)b * 262144 + e;
        float c2 = 0;
#pragma unroll 4
        for (int t2 = tq; t2 < len; t2 += 4) c2 += sh.sx.se[t2] * mb[(size_t)t2 * 512];
        sh.sx.red[tq * 64 + (tid & 63)] = c2;
        __syncthreads();
        if (tid < 64) {
          float cv = (sh.sx.red[tid] + sh.sx.red[64 + tid]) +
                     (sh.sx.red[128 + tid] + sh.sx.red[192 + tid]);
          ctxT[(size_t)(eblk * 64 + tid) * 64 + b] = cv;
        }
      }
      phase++; grid_sync(bar, phase * NB);
    }
  }
}

extern "C" void kernel_launch(void* const* d_in, const int* in_sizes, int n_in,
                              void* d_out, int out_size, void* d_ws, size_t ws_size,
                              hipStream_t stream) {
  const float* memory = (const float*)d_in[0];
  const int*   mlen   = (const int*)d_in[1];
  const float* dec_in = (const float*)d_in[2];
  const float* pw1    = (const float*)d_in[3];
  const float* pw2    = (const float*)d_in[4];
  const float* awih   = (const float*)d_in[5];
  const float* awhh   = (const float*)d_in[6];
  const float* abih   = (const float*)d_in[7];
  const float* abhh   = (const float*)d_in[8];
  const float* dwih   = (const float*)d_in[9];
  const float* dwhh   = (const float*)d_in[10];
  const float* dbih   = (const float*)d_in[11];
  const float* dbhh   = (const float*)d_in[12];
  const float* wq     = (const float*)d_in[13];
  const float* wm     = (const float*)d_in[14];
  const float* av     = (const float*)d_in[15];
  const float* wconv  = (const float*)d_in[16];
  const float* wld    = (const float*)d_in[17];
  const float* projw  = (const float*)d_in[18];
  const float* projb  = (const float*)d_in[19];
  const float* gatew  = (const float*)d_in[20];
  const float* gateb  = (const float*)d_in[21];

  float* out       = (float*)d_out;
  float* out_mel   = out;                 // 2,560,000
  float* out_gate  = out + 2560000;       // 32,000
  float* out_align = out + 2592000;       // 16,384,000

  if (ws_size < (size_t)WS_FLOATS_NEEDED * 4) return;

  float* ws = (float*)d_ws;
  // prenet layer-1 temp lives in the out_align region (fully rewritten later)
  float* tmp1 = out_align;

  hipMemsetAsync(ws + OFF_AHT, 0, (size_t)360448 * 4, stream);   // states
  hipMemsetAsync(ws + OFF_BAR, 0, 256, stream);                  // barrier

  k_fold<<<4, 256, 0, stream>>>((uint32_t*)(ws + OFF_KF));
  k_pm<<<4096, 256, 0, stream>>>(memory, wm, ws + OFF_PM);
  k_prenet1<<<4000, 256, 0, stream>>>(dec_in, pw1, tmp1);
  k_prenet2<<<4000, 256, 0, stream>>>(tmp1, pw2, ws + OFF_PRENETT);
  k_prep_wq<<<512, 256, 0, stream>>>(wq, ws + OFF_WQT);
  k_prep_pw<<<486, 256, 0, stream>>>(projw, gatew, ws + OFF_PWT);

  k_persist<<<NB, 256, 0, stream>>>(memory, mlen,
                                    awih, awhh, abih, abhh,
                                    dwih, dwhh, dbih, dbhh,
                                    wconv, wld, av, projb, gateb,
                                    out_mel, out_gate, out_align, ws);
}

// Round 3
// 191290.015 us; speedup vs baseline: 2.5856x; 2.5856x over previous
//
#include <hip/hip_runtime.h>
#include <cstdint>

// B=64 T=512 S=500 M=80 E=512 P=256 H=1024 A=128 F_LOC=32 K_LOC=31
// Persistent-kernel design: 1 kernel, 500 steps, 4 grid barriers/step.
// Stage A: attn-GEMM(s) + dec-GEMM(s-1)   [global-direct fp32 GEMM, no LDS]
// Stage B: attn pointwise+dropout+q(s) + dec pointwise+mel/gate(s-1)
// Stage C: location conv + energies + exp + tile sums (s)
// Stage D: softmax normalize + alignments + ctx (s)
//
// R3 fix: grid barrier uses RELEASE add + RELAXED spin + single ACQUIRE load.
// R2's ACQUIRE-in-spin-loop emitted buffer_inv per poll -> cache invalidation
// storm -> 49GB HBM refetch/dispatch at 115GB/s (the whole 494ms).

#define NB 512

// ---------------- workspace float offsets ----------------
#define OFF_PM      0u          // 64*512*128
#define OFF_PRENETT 4194304u    // [500][256][64]
#define OFF_PARTA   12386304u   // 7 *64*4096
#define OFF_PARTD   14221312u   // 10*64*4096
#define OFF_QPART   16842752u   // 4*64*128
#define OFF_PEXP    16875520u   // 64*512
#define OFF_ESUM    16908288u   // 64*8
#define OFF_AHT     16908800u   // [1024][64]
#define OFF_AC      16974336u   // [64][1024]
#define OFF_DHT     17039872u   // [1024][64]
#define OFF_DC      17105408u   // [64][1024]
#define OFF_AW      17170944u   // [64][512]
#define OFF_AWC     17203712u
#define OFF_CTXT    17236480u   // [512][64]
#define OFF_WQT     17269248u   // [1024][128]
#define OFF_PWT     17400320u   // [1536][81]
#define OFF_KF      17524736u   // 2000 u32
#define OFF_BAR     17526784u   // barrier counter
#define WS_FLOATS_NEEDED 17526848u

// ---------------- threefry RNG (JAX partitionable, scheme 0) ----------------
__device__ __forceinline__ void tf2x32(uint32_t k0, uint32_t k1, uint32_t& x0, uint32_t& x1) {
  uint32_t ks2 = k0 ^ k1 ^ 0x1BD11BDAu;
  x0 += k0; x1 += k1;
#define TFR(r) { x0 += x1; x1 = (x1 << (r)) | (x1 >> (32 - (r))); x1 ^= x0; }
  TFR(13) TFR(15) TFR(26) TFR(6)
  x0 += k1; x1 += ks2 + 1u;
  TFR(17) TFR(29) TFR(16) TFR(24)
  x0 += ks2; x1 += k0 + 2u;
  TFR(13) TFR(15) TFR(26) TFR(6)
  x0 += k0; x1 += k1 + 3u;
  TFR(17) TFR(29) TFR(16) TFR(24)
  x0 += k1; x1 += ks2 + 4u;
  TFR(13) TFR(15) TFR(26) TFR(6)
  x0 += ks2; x1 += k0 + 5u;
#undef TFR
}

__device__ __forceinline__ float rng_u01(uint32_t k0, uint32_t k1, uint32_t idx) {
  uint32_t x0 = 0u, x1 = idx;
  tf2x32(k0, k1, x0, x1);
  uint32_t b = x0 ^ x1;
  return __uint_as_float((b >> 9) | 0x3f800000u) - 1.0f;
}

__device__ __forceinline__ float sigmf(float x) { return 1.0f / (1.0f + expf(-x)); }

// ---------------- grid barrier (monotonic counter, cache-friendly) ----------------
// RELEASE add: one L2 writeback of this block's stage outputs, then signal.
// RELAXED spin: agent-scope atomic loads read through to the coherence point
//   (MALL) without invalidating L1/L2 -> cached weights survive the wait.
// Single ACQUIRE load on exit: one buffer_inv so we observe peers' writes.
__device__ __forceinline__ void grid_sync(int* bar, int target) {
  __syncthreads();
  if (threadIdx.x == 0) {
    __hip_atomic_fetch_add(bar, 1, __ATOMIC_RELEASE, __HIP_MEMORY_SCOPE_AGENT);
    while (__hip_atomic_load(bar, __ATOMIC_RELAXED, __HIP_MEMORY_SCOPE_AGENT) < target)
      __builtin_amdgcn_s_sleep(8);
    (void)__hip_atomic_load(bar, __ATOMIC_ACQUIRE, __HIP_MEMORY_SCOPE_AGENT);
  }
  __syncthreads();
}

// ---------------- prep kernels ----------------
__global__ void k_fold(uint32_t* __restrict__ kf) {
  int t = blockIdx.x * 256 + threadIdx.x;
  if (t < 1000) {
    uint32_t x0 = 0u, x1 = (uint32_t)t;
    tf2x32(0u, 7u, x0, x1);
    kf[2 * t] = x0; kf[2 * t + 1] = x1;
  }
}

__global__ __launch_bounds__(256) void k_pm(const float* __restrict__ mem,
                                            const float* __restrict__ wm,
                                            float* __restrict__ pm) {
  const int row0 = blockIdx.x * 8;  // flat (b*512+t)
  __shared__ float sm[8][512];
  const float4* src = (const float4*)(mem + (size_t)row0 * 512);
  float4* dst = (float4*)&sm[0][0];
  for (int i = threadIdx.x; i < 8 * 128; i += 256) dst[i] = src[i];
  __syncthreads();
  const int a = threadIdx.x & 127;
  const int rh = threadIdx.x >> 7;
  float acc[4] = {0.f, 0.f, 0.f, 0.f};
  for (int e = 0; e < 512; e += 4) {
    float4 w4 = *(const float4*)&wm[a * 512 + e];
#pragma unroll
    for (int r = 0; r < 4; r++) {
      acc[r] += sm[rh * 4 + r][e] * w4.x + sm[rh * 4 + r][e + 1] * w4.y +
                sm[rh * 4 + r][e + 2] * w4.z + sm[rh * 4 + r][e + 3] * w4.w;
    }
  }
#pragma unroll
  for (int r = 0; r < 4; r++) pm[(size_t)(row0 + rh * 4 + r) * 128 + a] = acc[r];
}

__global__ __launch_bounds__(256) void k_prenet1(const float* __restrict__ din,
                                                 const float* __restrict__ w1,
                                                 float* __restrict__ tmp1) {
  const int r0 = blockIdx.x * 8;
  const int tid = threadIdx.x;
  __shared__ float xin[8][80];
  for (int i = tid; i < 640; i += 256) {
    int rr = i / 80, k = i - rr * 80;
    int r = r0 + rr;
    int s = r >> 6, b = r & 63;
    xin[rr][k] = (s == 0) ? 0.0f : din[((size_t)b * 500 + (s - 1)) * 80 + k];
  }
  __syncthreads();
  const int j = tid;
  float acc[8] = {};
  for (int k = 0; k < 80; k++) {
    float wv = w1[j * 80 + k];
#pragma unroll
    for (int i = 0; i < 8; i++) acc[i] += xin[i][k] * wv;
  }
#pragma unroll
  for (int i = 0; i < 8; i++) {
    int r = r0 + i;
    float x = fmaxf(acc[i], 0.0f);
    float u = rng_u01(0u, 101u, (uint32_t)(r * 256 + j));
    x = (u < 0.5f) ? x * 2.0f : 0.0f;
    tmp1[(size_t)r * 256 + j] = x;
  }
}

__global__ __launch_bounds__(256) void k_prenet2(const float* __restrict__ tmp1,
                                                 const float* __restrict__ w2,
                                                 float* __restrict__ prenetT) {
  const int r0 = blockIdx.x * 8;
  const int s = r0 >> 6, b0 = r0 & 63;
  const int tid = threadIdx.x;
  __shared__ float xin[8][256];
  for (int i = tid; i < 2048; i += 256) xin[i >> 8][i & 255] = tmp1[(size_t)r0 * 256 + i];
  __syncthreads();
  const int j = tid;
  float acc[8] = {};
  for (int k = 0; k < 256; k++) {
    float wv = w2[j * 256 + k];
#pragma unroll
    for (int i = 0; i < 8; i++) acc[i] += xin[i][k] * wv;
  }
  float v[8];
#pragma unroll
  for (int i = 0; i < 8; i++) {
    int r = r0 + i;
    float x = fmaxf(acc[i], 0.0f);
    float u = rng_u01(0u, 102u, (uint32_t)(r * 256 + j));
    v[i] = (u < 0.5f) ? x * 2.0f : 0.0f;
  }
  float* dstp = prenetT + (size_t)s * 16384 + (size_t)j * 64 + b0;
  *(float4*)dstp = make_float4(v[0], v[1], v[2], v[3]);
  *(float4*)(dstp + 4) = make_float4(v[4], v[5], v[6], v[7]);
}

__global__ void k_prep_wq(const float* __restrict__ wq, float* __restrict__ wqT) {
  int idx = blockIdx.x * 256 + threadIdx.x;  // 1024*128
  if (idx < 131072) { int h = idx >> 7, a = idx & 127; wqT[idx] = wq[a * 1024 + h]; }
}

__global__ void k_prep_pw(const float* __restrict__ projw, const float* __restrict__ gatew,
                          float* __restrict__ pwT) {
  int idx = blockIdx.x * 256 + threadIdx.x;  // 1536*81
  if (idx < 124416) {
    int dim = idx / 81, m = idx - dim * 81;
    pwT[idx] = (m < 80) ? projw[(size_t)m * 1536 + dim] : gatew[dim];
  }
}

// ---------------- global-direct GEMM tile: 64j x 64b x 256k ----------------
// xT: [k][64b] transposed activations. w: row-major [j][K]. Writes part slab [b][4096].
__device__ __forceinline__ void gemm_tile(const float* __restrict__ xT,
                                          const float* __restrict__ w, int wst, int wcol,
                                          int j0, float* __restrict__ slab) {
  const int tid = threadIdx.x;
  const int bq4 = (tid & 15) * 4;
  const int jr0 = j0 + (tid >> 4) * 4;
  const float* wr0 = w + (size_t)jr0 * wst + wcol;
  const float* wr1 = wr0 + wst;
  const float* wr2 = wr1 + wst;
  const float* wr3 = wr2 + wst;
  float acc[4][4] = {};
#define FMAROW(jr, wv, xv) { acc[jr][0] += (wv)*(xv).x; acc[jr][1] += (wv)*(xv).y; \
                             acc[jr][2] += (wv)*(xv).z; acc[jr][3] += (wv)*(xv).w; }
  for (int k = 0; k < 256; k += 4) {
    float4 x0 = *(const float4*)(xT + (k + 0) * 64 + bq4);
    float4 x1 = *(const float4*)(xT + (k + 1) * 64 + bq4);
    float4 x2 = *(const float4*)(xT + (k + 2) * 64 + bq4);
    float4 x3 = *(const float4*)(xT + (k + 3) * 64 + bq4);
    float4 w0 = *(const float4*)(wr0 + k);
    float4 w1 = *(const float4*)(wr1 + k);
    float4 w2 = *(const float4*)(wr2 + k);
    float4 w3 = *(const float4*)(wr3 + k);
    FMAROW(0, w0.x, x0) FMAROW(1, w1.x, x0) FMAROW(2, w2.x, x0) FMAROW(3, w3.x, x0)
    FMAROW(0, w0.y, x1) FMAROW(1, w1.y, x1) FMAROW(2, w2.y, x1) FMAROW(3, w3.y, x1)
    FMAROW(0, w0.z, x2) FMAROW(1, w1.z, x2) FMAROW(2, w2.z, x2) FMAROW(3, w3.z, x2)
    FMAROW(0, w0.w, x3) FMAROW(1, w1.w, x3) FMAROW(2, w2.w, x3) FMAROW(3, w3.w, x3)
  }
#undef FMAROW
#pragma unroll
  for (int bb = 0; bb < 4; bb++) {
    *(float4*)&slab[(size_t)((tid & 15) * 4 + bb) * 4096 + jr0] =
        make_float4(acc[0][bb], acc[1][bb], acc[2][bb], acc[3][bb]);
  }
}

// ---------------- shared-memory union ----------------
struct EnS { float sa[2][96]; float sq[128]; float sv[128]; float sw[1984];
             float sld[4096]; float sloc[64][33]; float spart[64][4]; };
struct SbS { float ahs[256]; float qred[256]; };
struct SdS { float dhn[256]; float red[256]; };
struct SxS { float se[512]; float red[256]; };
union ShU { EnS en; SbS sb; SdS sd; SxS sx; };

// ---------------- the persistent kernel ----------------
__global__ __launch_bounds__(256, 2) void k_persist(
    const float* __restrict__ memory, const int* __restrict__ mlen,
    const float* __restrict__ awih, const float* __restrict__ awhh,
    const float* __restrict__ abih, const float* __restrict__ abhh,
    const float* __restrict__ dwih, const float* __restrict__ dwhh,
    const float* __restrict__ dbih, const float* __restrict__ dbhh,
    const float* __restrict__ wconv, const float* __restrict__ wld,
    const float* __restrict__ av,
    const float* __restrict__ projb, const float* __restrict__ gateb,
    float* __restrict__ out_mel, float* __restrict__ out_gate,
    float* __restrict__ out_align, float* __restrict__ ws) {
  const int bid = blockIdx.x, tid = threadIdx.x;
  float* pm      = ws + OFF_PM;
  float* prenetT = ws + OFF_PRENETT;
  float* part_a  = ws + OFF_PARTA;
  float* part_d  = ws + OFF_PARTD;
  float* qpart   = ws + OFF_QPART;
  float* pexp    = ws + OFF_PEXP;
  float* esum    = ws + OFF_ESUM;
  float* ahT     = ws + OFF_AHT;
  float* ac      = ws + OFF_AC;
  float* dhT     = ws + OFF_DHT;
  float* dc      = ws + OFF_DC;
  float* aw      = ws + OFF_AW;
  float* awc     = ws + OFF_AWC;
  float* ctxT    = ws + OFF_CTXT;
  float* wqT     = ws + OFF_WQT;
  float* pwT     = ws + OFF_PWT;
  const uint32_t* kf = (const uint32_t*)(ws + OFF_KF);
  int* bar = (int*)(ws + OFF_BAR);

  __shared__ ShU sh;

  int phase = 0;
  for (int i = 0; i <= 500; ++i) {
    // ================= Stage A: GEMMs (+ zero mel/gate slice s=i-1) =================
    if (i >= 1 && bid < 64) {
      if (tid < 80) out_mel[(size_t)bid * 40000 + (size_t)(i - 1) * 80 + tid] = 0.f;
      else if (tid == 80) out_gate[bid * 500 + (i - 1)] = 0.f;
    }
    for (int task = bid; task < 1088; task += NB) {
      if (task < 448) {
        if (i < 500) {
          int jt = task / 7, kc = task - jt * 7;
          const float* xT; const float* w; int wst, wcol;
          if (kc == 0)      { xT = prenetT + (size_t)i * 16384; w = awih; wst = 768; wcol = 0; }
          else if (kc <= 2) { xT = ctxT + (size_t)(kc - 1) * 16384; w = awih; wst = 768; wcol = kc * 256; }
          else              { xT = ahT + (size_t)(kc - 3) * 16384; w = awhh; wst = 1024; wcol = (kc - 3) * 256; }
          gemm_tile(xT, w, wst, wcol, jt * 64, part_a + (size_t)kc * 262144);
        }
      } else {
        if (i >= 1) {
          int t2 = task - 448;
          int jt = t2 / 10, kc = t2 - jt * 10;
          const float* xT; const float* w; int wst, wcol;
          if (kc <= 3)      { xT = ahT + (size_t)kc * 16384; w = dwih; wst = 1536; wcol = kc * 256; }
          else if (kc <= 5) { xT = ctxT + (size_t)(kc - 4) * 16384; w = dwih; wst = 1536; wcol = 1024 + (kc - 4) * 256; }
          else              { xT = dhT + (size_t)(kc - 6) * 16384; w = dwhh; wst = 1024; wcol = (kc - 6) * 256; }
          gemm_tile(xT, w, wst, wcol, jt * 64, part_d + (size_t)kc * 262144);
        }
      }
    }
    phase++; grid_sync(bar, phase * NB);

    // ================= Stage B: pointwise =================
    if (bid < 256) {
      if (i < 500) {  // attn LSTM pointwise + dropout + q partial
        const int b = bid >> 2, hblk = bid & 3;
        const int h = hblk * 256 + tid;
        const float* pa = part_a + (size_t)b * 4096 + h;
        float gi = abih[h] + abhh[h];
        float gf = abih[1024 + h] + abhh[1024 + h];
        float gg = abih[2048 + h] + abhh[2048 + h];
        float go = abih[3072 + h] + abhh[3072 + h];
#pragma unroll
        for (int p = 0; p < 7; p++) {
          const float* pp = pa + (size_t)p * 262144;
          gi += pp[0]; gf += pp[1024]; gg += pp[2048]; go += pp[3072];
        }
        float c = sigmf(gf) * ac[b * 1024 + h] + sigmf(gi) * tanhf(gg);
        float hn = sigmf(go) * tanhf(c);
        ac[b * 1024 + h] = c;
        float u = rng_u01(kf[4 * i], kf[4 * i + 1], (uint32_t)(b * 1024 + h));
        hn = (u < 0.9f) ? hn / 0.9f : 0.0f;
        ahT[(size_t)h * 64 + b] = hn;
        sh.sb.ahs[tid] = hn;
        __syncthreads();
        const int a = tid & 127, hh = tid >> 7;
        const float* wqp = wqT + (size_t)(hblk * 256 + hh * 128) * 128 + a;
        const float* hp = sh.sb.ahs + hh * 128;
        float acq = 0;
#pragma unroll 4
        for (int k = 0; k < 128; k++) acq += hp[k] * wqp[(size_t)k * 128];
        sh.sb.qred[tid] = acq;
        __syncthreads();
        if (tid < 128) qpart[hblk * 8192 + b * 128 + tid] = sh.sb.qred[tid] + sh.sb.qred[128 + tid];
      }
    } else {
      if (i >= 1) {  // dec LSTM pointwise + dropout + mel/gate partial
        const int u2 = bid - 256, b = u2 >> 2, hblk = u2 & 3, so = i - 1;
        const int h = hblk * 256 + tid;
        const float* pd = part_d + (size_t)b * 4096 + h;
        float gi = dbih[h] + dbhh[h];
        float gf = dbih[1024 + h] + dbhh[1024 + h];
        float gg = dbih[2048 + h] + dbhh[2048 + h];
        float go = dbih[3072 + h] + dbhh[3072 + h];
#pragma unroll
        for (int p = 0; p < 10; p++) {
          const float* pp = pd + (size_t)p * 262144;
          gi += pp[0]; gf += pp[1024]; gg += pp[2048]; go += pp[3072];
        }
        float c = sigmf(gf) * dc[b * 1024 + h] + sigmf(gi) * tanhf(gg);
        float hn = sigmf(go) * tanhf(c);
        dc[b * 1024 + h] = c;
        float u = rng_u01(kf[4 * so + 2], kf[4 * so + 3], (uint32_t)(b * 1024 + h));
        hn = (u < 0.9f) ? hn / 0.9f : 0.0f;
        dhT[(size_t)h * 64 + b] = hn;
        sh.sd.dhn[tid] = hn;
        __syncthreads();
        float partial = 0.f;
        if (tid < 162) {
          const int seg = (tid >= 81) ? 1 : 0;
          const int m = tid - seg * 81;
          const int dbase = hblk * 256 + seg * 128;
          const float* pwp = pwT + (size_t)dbase * 81 + m;
          float a1 = 0;
#pragma unroll 4
          for (int d = 0; d < 128; d++) a1 += sh.sd.dhn[seg * 128 + d] * pwp[(size_t)d * 81];
          if (hblk < 2) {
            const int ebase = hblk * 256 + seg * 128;
            const float* pwc = pwT + (size_t)(1024 + ebase) * 81 + m;
            const float* cxp = ctxT + (size_t)ebase * 64 + b;
#pragma unroll 4
            for (int d = 0; d < 128; d++) a1 += cxp[(size_t)d * 64] * pwc[(size_t)d * 81];
          }
          partial = a1;
        }
        sh.sd.red[tid] = partial;
        __syncthreads();
        if (tid < 81) {
          float tot = sh.sd.red[tid] + sh.sd.red[81 + tid];
          if (hblk == 0) tot += (tid < 80) ? projb[tid] : gateb[0];
          if (tid < 80) atomicAdd(&out_mel[(size_t)b * 40000 + (size_t)so * 80 + tid], tot);
          else          atomicAdd(&out_gate[b * 500 + so], tot);
        }
      }
    }
    phase++; grid_sync(bar, phase * NB);

    if (i < 500) {
      // ================= Stage C: energies → exp + tile sums =================
      {
        const int b = bid >> 3, ttile = bid & 7, t0 = ttile * 64;
        const int t = tid & 63, aq = tid >> 6;
        for (int i2 = tid; i2 < 94; i2 += 256) {
          int tt = t0 - 15 + i2;
          bool ok = (tt >= 0 && tt < 512);
          sh.en.sa[0][i2] = ok ? aw[b * 512 + tt] : 0.0f;
          sh.en.sa[1][i2] = ok ? awc[b * 512 + tt] : 0.0f;
        }
        if (tid < 128) {
          sh.en.sq[tid] = qpart[b * 128 + tid] + qpart[8192 + b * 128 + tid] +
                          qpart[16384 + b * 128 + tid] + qpart[24576 + b * 128 + tid];
          sh.en.sv[tid] = av[tid];
        }
        for (int i2 = tid; i2 < 1984; i2 += 256) sh.en.sw[i2] = wconv[i2];
        for (int i2 = tid; i2 < 4096; i2 += 256) sh.en.sld[i2] = wld[i2];
        __syncthreads();
        const int len = mlen[b];
        const int tt = t0 + t;
        const bool act2 = (tt < len);
        if (act2) {
          for (int f = aq * 8; f < aq * 8 + 8; f++) {
            const float* w0 = sh.en.sw + f * 62;
            const float* w1 = w0 + 31;
            float a2 = 0;
#pragma unroll
            for (int k = 0; k < 31; k++) a2 += sh.en.sa[0][t + k] * w0[k] + sh.en.sa[1][t + k] * w1[k];
            sh.en.sloc[t][f] = a2;
          }
        }
        __syncthreads();
        if (act2) {
          const float* pmr = pm + (size_t)(b * 512 + tt) * 128;
          float acc2 = 0;
          for (int a = aq * 32; a < aq * 32 + 32; a++) {
            float pl = 0;
#pragma unroll
            for (int f = 0; f < 32; f++) pl += sh.en.sloc[t][f] * sh.en.sld[a * 32 + f];
            float x = sh.en.sq[a] + pl + pmr[a];
            float ex = __expf(2.0f * x);
            acc2 += sh.en.sv[a] * (1.0f - 2.0f / (ex + 1.0f));
          }
          sh.en.spart[t][aq] = acc2;
        }
        __syncthreads();
        if (tid < 64) {
          int g = t0 + tid;
          float pe = 0.0f;
          if (g < len) {
            float e = (sh.en.spart[tid][0] + sh.en.spart[tid][1]) +
                      (sh.en.spart[tid][2] + sh.en.spart[tid][3]);
            pe = __expf(e);  // |e| <= sum|v| ~ 2, no max-subtraction needed
          }
          pexp[b * 512 + g] = pe;
          float ssum = pe;
          for (int off = 32; off > 0; off >>= 1) ssum += __shfl_down(ssum, off);
          if (tid == 0) esum[b * 8 + ttile] = ssum;
        }
      }
      phase++; grid_sync(bar, phase * NB);

      // ================= Stage D: normalize + alignments + ctx =================
      {
        const int b = bid >> 3, eblk = bid & 7;
        const int len = mlen[b];
        float S = 0;
#pragma unroll
        for (int p = 0; p < 8; p++) S += esum[b * 8 + p];
        const float rS = 1.0f / S;
        for (int t2 = tid; t2 < 512; t2 += 256) sh.sx.se[t2] = pexp[b * 512 + t2] * rS;
        __syncthreads();
        if (eblk == 0) {
          for (int t2 = tid; t2 < 512; t2 += 256) {
            float a2 = sh.sx.se[t2];
            aw[b * 512 + t2] = a2;
            awc[b * 512 + t2] += a2;
            out_align[(size_t)b * 256000 + (size_t)i * 512 + t2] = a2;
          }
        }
        const int e = eblk * 64 + (tid & 63), tq = tid >> 6;
        const float* mb = memory + (size_t)b * 262144 + e;
        float c2 = 0;
#pragma unroll 4
        for (int t2 = tq; t2 < len; t2 += 4) c2 += sh.sx.se[t2] * mb[(size_t)t2 * 512];
        sh.sx.red[tq * 64 + (tid & 63)] = c2;
        __syncthreads();
        if (tid < 64) {
          float cv = (sh.sx.red[tid] + sh.sx.red[64 + tid]) +
                     (sh.sx.red[128 + tid] + sh.sx.red[192 + tid]);
          ctxT[(size_t)(eblk * 64 + tid) * 64 + b] = cv;
        }
      }
      phase++; grid_sync(bar, phase * NB);
    }
  }
}

extern "C" void kernel_launch(void* const* d_in, const int* in_sizes, int n_in,
                              void* d_out, int out_size, void* d_ws, size_t ws_size,
                              hipStream_t stream) {
  const float* memory = (const float*)d_in[0];
  const int*   mlen   = (const int*)d_in[1];
  const float* dec_in = (const float*)d_in[2];
  const float* pw1    = (const float*)d_in[3];
  const float* pw2    = (const float*)d_in[4];
  const float* awih   = (const float*)d_in[5];
  const float* awhh   = (const float*)d_in[6];
  const float* abih   = (const float*)d_in[7];
  const float* abhh   = (const float*)d_in[8];
  const float* dwih   = (const float*)d_in[9];
  const float* dwhh   = (const float*)d_in[10];
  const float* dbih   = (const float*)d_in[11];
  const float* dbhh   = (const float*)d_in[12];
  const float* wq     = (const float*)d_in[13];
  const float* wm     = (const float*)d_in[14];
  const float* av     = (const float*)d_in[15];
  const float* wconv  = (const float*)d_in[16];
  const float* wld    = (const float*)d_in[17];
  const float* projw  = (const float*)d_in[18];
  const float* projb  = (const float*)d_in[19];
  const float* gatew  = (const float*)d_in[20];
  const float* gateb  = (const float*)d_in[21];

  float* out       = (float*)d_out;
  float* out_mel   = out;                 // 2,560,000
  float* out_gate  = out + 2560000;       // 32,000
  float* out_align = out + 2592000;       // 16,384,000

  if (ws_size < (size_t)WS_FLOATS_NEEDED * 4) return;

  float* ws = (float*)d_ws;
  // prenet layer-1 temp lives in the out_align region (fully rewritten later)
  float* tmp1 = out_align;

  hipMemsetAsync(ws + OFF_AHT, 0, (size_t)360448 * 4, stream);   // states
  hipMemsetAsync(ws + OFF_BAR, 0, 256, stream);                  // barrier

  k_fold<<<4, 256, 0, stream>>>((uint32_t*)(ws + OFF_KF));
  k_pm<<<4096, 256, 0, stream>>>(memory, wm, ws + OFF_PM);
  k_prenet1<<<4000, 256, 0, stream>>>(dec_in, pw1, tmp1);
  k_prenet2<<<4000, 256, 0, stream>>>(tmp1, pw2, ws + OFF_PRENETT);
  k_prep_wq<<<512, 256, 0, stream>>>(wq, ws + OFF_WQT);
  k_prep_pw<<<486, 256, 0, stream>>>(projw, gatew, ws + OFF_PWT);

  k_persist<<<NB, 256, 0, stream>>>(memory, mlen,
                                    awih, awhh, abih, abhh,
                                    dwih, dwhh, dbih, dbhh,
                                    wconv, wld, av, projb, gateb,
                                    out_mel, out_gate, out_align, ws);
}